// Round 15
// 409.618 us; speedup vs baseline: 9.0321x; 1.0129x over previous
//
#include <hip/hip_runtime.h>

#define LAMBDA_INIT 0.2f
#define SCALING 0.17677669529663687f   // 1/sqrt(32)
#define EPS_DEF 1.1920928955078125e-07f
#define EPS_ATTN 1e-5f

typedef unsigned short us4 __attribute__((ext_vector_type(4)));
typedef unsigned short us8v __attribute__((ext_vector_type(8)));
typedef float f32x4 __attribute__((ext_vector_type(4)));
typedef float f32x2 __attribute__((ext_vector_type(2)));
typedef __bf16 bf16x8 __attribute__((ext_vector_type(8)));

#define MFMA16(a, b, c) __builtin_amdgcn_mfma_f32_16x16x32_bf16((a), (b), (c), 0, 0, 0)

__device__ __forceinline__ float bf2f(unsigned short u) {
    unsigned int x = ((unsigned int)u) << 16;
    return __builtin_bit_cast(float, x);
}
__device__ __forceinline__ unsigned short f2bf(float f) {
    unsigned int x = __builtin_bit_cast(unsigned int, f);
    x += 0x7fffu + ((x >> 16) & 1u);
    return (unsigned short)(x >> 16);
}
// split a pair of f32x4 into hi/lo bf16 (x ~= hi + lo, residual ~2^-18 rel)
__device__ __forceinline__ void split8(f32x4 a, f32x4 b, us8v& hi, us8v& lo) {
#pragma unroll
    for (int u = 0; u < 4; u++) {
        unsigned short h = f2bf(a[u]);
        hi[u] = h; lo[u] = f2bf(a[u] - bf2f(h));
        unsigned short h2 = f2bf(b[u]);
        hi[4 + u] = h2; lo[4 + u] = f2bf(b[u] - bf2f(h2));
    }
}
__device__ __forceinline__ bf16x8 ldb(const unsigned short* p) {
    return __builtin_bit_cast(bf16x8, *(const us8v*)p);
}
// RoPE on 4 consecutive dims starting at dd (within head)
__device__ __forceinline__ f32x4 rope4(f32x4 v, const float* __restrict__ fc, int p, int dd) {
    if (p == 0) return v;
    int d4 = (dd & 31) >> 1;
    f32x4 f = *(const f32x4*)(fc + ((size_t)(p - 1) * 16 + d4) * 2);
    f32x4 o;
    o[0] = v[0] * f[0] - v[1] * f[1];
    o[1] = v[0] * f[1] + v[1] * f[0];
    o[2] = v[2] * f[2] - v[3] * f[3];
    o[3] = v[2] * f[3] + v[3] * f[2];
    return o;
}

__device__ __forceinline__ float wave_sum(float v) {
#pragma unroll
    for (int o = 32; o > 0; o >>= 1) v += __shfl_down(v, o);
    return v;
}
__device__ __forceinline__ float block_sum(float v, float* red4) {
    int wv = threadIdx.x >> 6;
    float w = wave_sum(v);
    __syncthreads();
    if ((threadIdx.x & 63) == 0) red4[wv] = w;
    __syncthreads();
    return red4[0] + red4[1] + red4[2] + red4[3];
}

// ---------------- prep: zero G + MZ, compute lambda ----------------
__global__ __launch_bounds__(256) void prep(float* __restrict__ G, float* __restrict__ MZ,
                                            float* __restrict__ lamp,
                                            const float* lq1, const float* lk1,
                                            const float* lq2, const float* lk2) {
    int i = (blockIdx.x * 256 + threadIdx.x) * 4;
    if (i < 32768) {
        G[i] = 0.f; G[i + 1] = 0.f; G[i + 2] = 0.f; G[i + 3] = 0.f;
    } else {
        int j = i - 32768;   // 65536 floats of MZ
        MZ[j] = 0.f; MZ[j + 1] = 0.f; MZ[j + 2] = 0.f; MZ[j + 3] = 0.f;
    }
    if (blockIdx.x == 0 && threadIdx.x == 0) {
        float a = 0.f, c = 0.f;
        for (int d = 0; d < 32; d++) {
            a += lq1[d] * lk1[d];
            c += lq2[d] * lk2[d];
        }
        *lamp = expf(a) - expf(c) + LAMBDA_INIT;
    }
}

// ------- QKV weight hi/lo splits + Wo plain bf16, one fused launch -------
__global__ __launch_bounds__(256) void cvt_wsplit(
        const float* __restrict__ s0, const float* __restrict__ s1,
        const float* __restrict__ s2, const float* __restrict__ s3,
        unsigned short* __restrict__ h0, unsigned short* __restrict__ l0,
        unsigned short* __restrict__ h1p, unsigned short* __restrict__ l1p,
        unsigned short* __restrict__ h2p, unsigned short* __restrict__ l2p,
        unsigned short* __restrict__ d3, int n4) {
    const int z = blockIdx.y;
    int i = blockIdx.x * 256 + threadIdx.x;
    if (i >= n4) return;
    if (z == 3) {   // plain bf16 convert (Wo)
        f32x4 v = ((const f32x4*)s3)[i];
        us4 o;
#pragma unroll
        for (int u = 0; u < 4; u++) o[u] = f2bf(v[u]);
        ((us4*)d3)[i] = o;
        return;
    }
    const float* s = (z == 0) ? s0 : (z == 1) ? s1 : s2;
    unsigned short* hi = (z == 0) ? h0 : (z == 1) ? h1p : h2p;
    unsigned short* lo = (z == 0) ? l0 : (z == 1) ? l1p : l2p;
    f32x4 v = ((const f32x4*)s)[i];
    us4 h, l;
#pragma unroll
    for (int u = 0; u < 4; u++) {
        h[u] = f2bf(v[u]);
        l[u] = f2bf(v[u] - bf2f(h[u]));
    }
    ((us4*)hi)[i] = h;
    ((us4*)lo)[i] = l;
}

// ------- gate weights (Wu | Wv) bf16 conversion, one fused launch -------
__global__ __launch_bounds__(256) void cvt_gate2(const float* __restrict__ Wg,
                                                 unsigned short* __restrict__ WuB,
                                                 unsigned short* __restrict__ WvB, int n4) {
    const int z = blockIdx.y;
    const float* s = Wg + (size_t)z * 4194304;
    unsigned short* d = z ? WvB : WuB;
    int i = blockIdx.x * 256 + threadIdx.x;
    if (i >= n4) return;
    f32x4 v = ((const f32x4*)s)[i];
    us4 o;
#pragma unroll
    for (int u = 0; u < 4; u++) o[u] = f2bf(v[u]);
    ((us4*)d)[i] = o;
}

// ---------------- fp32 -> bf16 conversion ----------------
__global__ __launch_bounds__(256) void cvt_bf16(const float* __restrict__ s,
                                                unsigned short* __restrict__ d, int n4) {
    int i = blockIdx.x * 256 + threadIdx.x;
    if (i >= n4) return;
    f32x4 v = ((const f32x4*)s)[i];
    us4 o;
#pragma unroll
    for (int u = 0; u < 4; u++) o[u] = f2bf(v[u]);
    ((us4*)d)[i] = o;
}

// ---------------- RMSNorm: fp32 in, fp32 weight, bf16/fp32 out ----------------
template <int OUTBF>
__global__ __launch_bounds__(256) void rms_kernel(const float* __restrict__ x,
                                                  const float* __restrict__ w,
                                                  void* __restrict__ out, float eps) {
    int row = blockIdx.x;
    int tid = threadIdx.x;
    size_t base = (size_t)row * 1024 + tid * 4;
    f32x4 v = *(const f32x4*)(x + base);
    float ss = v[0]*v[0] + v[1]*v[1] + v[2]*v[2] + v[3]*v[3];
    __shared__ float red4[4];
    float tot = block_sum(ss, red4);
    float r = rsqrtf(tot * (1.0f / 1024.f) + eps);
    f32x4 wv = *(const f32x4*)(w + tid * 4);
    if (OUTBF) {
        us4 o;
#pragma unroll
        for (int i = 0; i < 4; i++) o[i] = f2bf(v[i] * r * wv[i]);
        *(us4*)((unsigned short*)out + base) = o;
    } else {
        f32x4 o;
#pragma unroll
        for (int i = 0; i < 4; i++) o[i] = v[i] * r * wv[i];
        *(f32x4*)((float*)out + base) = o;
    }
}

// ---------------- RMSNorm with hi/lo split output ----------------
__global__ __launch_bounds__(256) void rms_split(const float* __restrict__ x,
                                                 const float* __restrict__ w,
                                                 unsigned short* __restrict__ hh,
                                                 unsigned short* __restrict__ hl, float eps) {
    int row = blockIdx.x;
    int tid = threadIdx.x;
    size_t base = (size_t)row * 1024 + tid * 4;
    f32x4 v = *(const f32x4*)(x + base);
    float ss = v[0]*v[0] + v[1]*v[1] + v[2]*v[2] + v[3]*v[3];
    __shared__ float red4[4];
    float tot = block_sum(ss, red4);
    float r = rsqrtf(tot * (1.0f / 1024.f) + eps);
    f32x4 wv = *(const f32x4*)(w + tid * 4);
    us4 oh, ol;
#pragma unroll
    for (int i = 0; i < 4; i++) {
        float val = v[i] * r * wv[i];
        oh[i] = f2bf(val);
        ol[i] = f2bf(val - bf2f(oh[i]));
    }
    *(us4*)(hh + base) = oh;
    *(us4*)(hl + base) = ol;
}

// =====================================================================
// QKV split-bf16 MFMA GEMM, PRE-SPLIT operands, SOFTWARE-PIPELINED.
// BM=64, BN=64, BK=64, 4 waves (2x2). Grid (32,16,3).
// =====================================================================
__global__ __launch_bounds__(256) void gemm_qkv_ps(
        const unsigned short* __restrict__ AH, const unsigned short* __restrict__ AL,
        const unsigned short* __restrict__ WqH, const unsigned short* __restrict__ WqL,
        const unsigned short* __restrict__ WkH, const unsigned short* __restrict__ WkL,
        const unsigned short* __restrict__ WvH, const unsigned short* __restrict__ WvL,
        const float* __restrict__ bq, const float* __restrict__ bk, const float* __restrict__ bv,
        float* __restrict__ Yq, float* __restrict__ Yk, float* __restrict__ Yv) {
    const int z = blockIdx.z;
    const unsigned short* BH = (z == 0) ? WqH : (z == 1) ? WkH : WvH;
    const unsigned short* BL = (z == 0) ? WqL : (z == 1) ? WkL : WvL;
    const float* bias = (z == 0) ? bq : (z == 1) ? bk : bv;
    float* out        = (z == 0) ? Yq : (z == 1) ? Yk : Yv;
    const int K = 1024, N = 1024;
    __shared__ __align__(16) unsigned short Ah[64][72];
    __shared__ __align__(16) unsigned short Al[64][72];
    __shared__ __align__(16) unsigned short Bh[64][72];
    __shared__ __align__(16) unsigned short Bl[64][72];
    const int t = threadIdx.x;
    const int bm = blockIdx.x, bn = blockIdx.y;
    const int lane = t & 63, w = t >> 6;
    const int wr = w >> 1, wc = w & 1;
    const int l15 = lane & 15, lg = lane >> 4;
    const int sr = t >> 2, sc = (t & 3) * 16;

    const unsigned short* AgH = AH + (size_t)(bm * 64 + sr) * K + sc;
    const unsigned short* AgL = AL + (size_t)(bm * 64 + sr) * K + sc;
    const unsigned short* BgH = BH + (size_t)(bn * 64 + sr) * K + sc;
    const unsigned short* BgL = BL + (size_t)(bn * 64 + sr) * K + sc;

    f32x4 acc[2][2] = {};

    us8v ah0 = *(const us8v*)AgH, ah1 = *(const us8v*)(AgH + 8);
    us8v al0 = *(const us8v*)AgL, al1 = *(const us8v*)(AgL + 8);
    us8v bh0 = *(const us8v*)BgH, bh1 = *(const us8v*)(BgH + 8);
    us8v bl0 = *(const us8v*)BgL, bl1 = *(const us8v*)(BgL + 8);

    for (int k0 = 0; k0 < K; k0 += 64) {
        __syncthreads();
        *(us8v*)&Ah[sr][sc] = ah0; *(us8v*)&Ah[sr][sc + 8] = ah1;
        *(us8v*)&Al[sr][sc] = al0; *(us8v*)&Al[sr][sc + 8] = al1;
        *(us8v*)&Bh[sr][sc] = bh0; *(us8v*)&Bh[sr][sc + 8] = bh1;
        *(us8v*)&Bl[sr][sc] = bl0; *(us8v*)&Bl[sr][sc + 8] = bl1;
        __syncthreads();
        if (k0 + 64 < K) {
            const int kn = k0 + 64;
            ah0 = *(const us8v*)(AgH + kn); ah1 = *(const us8v*)(AgH + kn + 8);
            al0 = *(const us8v*)(AgL + kn); al1 = *(const us8v*)(AgL + kn + 8);
            bh0 = *(const us8v*)(BgH + kn); bh1 = *(const us8v*)(BgH + kn + 8);
            bl0 = *(const us8v*)(BgL + kn); bl1 = *(const us8v*)(BgL + kn + 8);
        }
#pragma unroll
        for (int kk = 0; kk < 2; kk++) {
            bf16x8 afh[2], afl[2], bfh[2], bfl[2];
#pragma unroll
            for (int mi = 0; mi < 2; mi++) {
                afh[mi] = ldb(&Ah[wr * 32 + mi * 16 + l15][kk * 32 + lg * 8]);
                afl[mi] = ldb(&Al[wr * 32 + mi * 16 + l15][kk * 32 + lg * 8]);
            }
#pragma unroll
            for (int ni = 0; ni < 2; ni++) {
                bfh[ni] = ldb(&Bh[wc * 32 + ni * 16 + l15][kk * 32 + lg * 8]);
                bfl[ni] = ldb(&Bl[wc * 32 + ni * 16 + l15][kk * 32 + lg * 8]);
            }
#pragma unroll
            for (int mi = 0; mi < 2; mi++)
#pragma unroll
                for (int ni = 0; ni < 2; ni++) {
                    acc[mi][ni] = MFMA16(afl[mi], bfh[ni], acc[mi][ni]);
                    acc[mi][ni] = MFMA16(afh[mi], bfl[ni], acc[mi][ni]);
                    acc[mi][ni] = MFMA16(afh[mi], bfh[ni], acc[mi][ni]);
                }
        }
    }

    const int rbase = bm * 64 + wr * 32 + (lg << 2);
    const int cbase = bn * 64 + wc * 32 + l15;
#pragma unroll
    for (int mi = 0; mi < 2; mi++) {
#pragma unroll
        for (int ni = 0; ni < 2; ni++) {
            int col = cbase + ni * 16;
            float bb = bias[col];
#pragma unroll
            for (int r = 0; r < 4; r++) {
                int row = rbase + mi * 16 + r;
                out[(size_t)row * N + col] = acc[mi][ni][r] + bb;
            }
        }
    }
}

// =====================================================================
// bf16 MFMA GEMM, pre-converted bf16 B, SOFTWARE-PIPELINED, BK=128.
// BM=64, BN=64, 4 waves (2x2). K must be a multiple of 128.
// =====================================================================
__global__ __launch_bounds__(256) void gemm_mfma_wb(const unsigned short* __restrict__ A,
                                                    const unsigned short* __restrict__ Bt,
                                                    const float* __restrict__ bias,
                                                    const float* __restrict__ res,
                                                    float* __restrict__ out,
                                                    int M, int N, int K) {
    __shared__ __align__(16) unsigned short As[64][136];
    __shared__ __align__(16) unsigned short Bs[64][136];
    const int t = threadIdx.x;
    const int bm = blockIdx.x, bn = blockIdx.y;
    const int lane = t & 63, w = t >> 6;
    const int wr = w >> 1, wc = w & 1;
    const int l15 = lane & 15, lg = lane >> 4;
    const int sr = t >> 2, sc = (t & 3) * 32;

    const unsigned short* Ag = A + (size_t)(bm * 64 + sr) * K + sc;
    const unsigned short* Bg = Bt + (size_t)(bn * 64 + sr) * K + sc;

    f32x4 acc[2][2] = {};

    us8v a0 = *(const us8v*)Ag,        a1 = *(const us8v*)(Ag + 8);
    us8v a2 = *(const us8v*)(Ag + 16), a3 = *(const us8v*)(Ag + 24);
    us8v b0 = *(const us8v*)Bg,        b1 = *(const us8v*)(Bg + 8);
    us8v b2 = *(const us8v*)(Bg + 16), b3 = *(const us8v*)(Bg + 24);

    for (int k0 = 0; k0 < K; k0 += 128) {
        __syncthreads();
        *(us8v*)&As[sr][sc]      = a0;
        *(us8v*)&As[sr][sc + 8]  = a1;
        *(us8v*)&As[sr][sc + 16] = a2;
        *(us8v*)&As[sr][sc + 24] = a3;
        *(us8v*)&Bs[sr][sc]      = b0;
        *(us8v*)&Bs[sr][sc + 8]  = b1;
        *(us8v*)&Bs[sr][sc + 16] = b2;
        *(us8v*)&Bs[sr][sc + 24] = b3;
        __syncthreads();
        if (k0 + 128 < K) {
            const int kn = k0 + 128;
            a0 = *(const us8v*)(Ag + kn);      a1 = *(const us8v*)(Ag + kn + 8);
            a2 = *(const us8v*)(Ag + kn + 16); a3 = *(const us8v*)(Ag + kn + 24);
            b0 = *(const us8v*)(Bg + kn);      b1 = *(const us8v*)(Bg + kn + 8);
            b2 = *(const us8v*)(Bg + kn + 16); b3 = *(const us8v*)(Bg + kn + 24);
        }
#pragma unroll
        for (int kk = 0; kk < 4; kk++) {
            bf16x8 af[2], bf[2];
#pragma unroll
            for (int mi = 0; mi < 2; mi++)
                af[mi] = ldb(&As[wr * 32 + mi * 16 + l15][kk * 32 + lg * 8]);
#pragma unroll
            for (int ni = 0; ni < 2; ni++)
                bf[ni] = ldb(&Bs[wc * 32 + ni * 16 + l15][kk * 32 + lg * 8]);
#pragma unroll
            for (int mi = 0; mi < 2; mi++)
#pragma unroll
                for (int ni = 0; ni < 2; ni++)
                    acc[mi][ni] = MFMA16(af[mi], bf[ni], acc[mi][ni]);
        }
    }

    const int rbase = bm * 64 + wr * 32 + (lg << 2);
    const int cbase = bn * 64 + wc * 32 + l15;
#pragma unroll
    for (int mi = 0; mi < 2; mi++) {
#pragma unroll
        for (int ni = 0; ni < 2; ni++) {
            int col = cbase + ni * 16;
            float bb = bias[col];
#pragma unroll
            for (int r = 0; r < 4; r++) {
                int row = rbase + mi * 16 + r;
                size_t oi = (size_t)row * N + col;
                out[oi] = acc[mi][ni][r] + bb + res[oi];
            }
        }
    }
}

// ------- fused gate GEMM, PRE-CONVERTED bf16 weights, PIPELINED -------
__global__ __launch_bounds__(256) void gemm_gate_wb(const unsigned short* __restrict__ A,
                                                    const unsigned short* __restrict__ WuB,
                                                    const unsigned short* __restrict__ WvB,
                                                    const float* __restrict__ bg,
                                                    unsigned short* __restrict__ mlp) {
    __shared__ __align__(16) unsigned short As[128][72];
    __shared__ __align__(16) unsigned short BsU[64][72];
    __shared__ __align__(16) unsigned short BsV[64][72];
    const int t = threadIdx.x;
    const int bm = blockIdx.x, bn = blockIdx.y;
    const int lane = t & 63, w = t >> 6;
    const int wr = w >> 1, wc = w & 1;
    const int l15 = lane & 15, lg = lane >> 4;
    const int sr = t >> 2, sc = (t & 3) * 16;

    const unsigned short* Ag  = A + (size_t)(bm * 128 + sr) * 1024 + sc;
    const unsigned short* Ag2 = Ag + (size_t)64 * 1024;
    const unsigned short* BgU = WuB + (size_t)(bn * 64 + sr) * 1024 + sc;
    const unsigned short* BgV = WvB + (size_t)(bn * 64 + sr) * 1024 + sc;

    f32x4 accU[4][2] = {};
    f32x4 accV[4][2] = {};

    us8v a0 = *(const us8v*)Ag,  a1 = *(const us8v*)(Ag + 8);
    us8v a2 = *(const us8v*)Ag2, a3 = *(const us8v*)(Ag2 + 8);
    us8v u0 = *(const us8v*)BgU, u1 = *(const us8v*)(BgU + 8);
    us8v v0 = *(const us8v*)BgV, v1 = *(const us8v*)(BgV + 8);

    for (int k0 = 0; k0 < 1024; k0 += 64) {
        __syncthreads();
        *(us8v*)&As[sr][sc]          = a0;
        *(us8v*)&As[sr][sc + 8]      = a1;
        *(us8v*)&As[sr + 64][sc]     = a2;
        *(us8v*)&As[sr + 64][sc + 8] = a3;
        *(us8v*)&BsU[sr][sc]         = u0;
        *(us8v*)&BsU[sr][sc + 8]     = u1;
        *(us8v*)&BsV[sr][sc]         = v0;
        *(us8v*)&BsV[sr][sc + 8]     = v1;
        __syncthreads();
        if (k0 + 64 < 1024) {
            const int kn = k0 + 64;
            a0 = *(const us8v*)(Ag + kn);  a1 = *(const us8v*)(Ag + kn + 8);
            a2 = *(const us8v*)(Ag2 + kn); a3 = *(const us8v*)(Ag2 + kn + 8);
            u0 = *(const us8v*)(BgU + kn); u1 = *(const us8v*)(BgU + kn + 8);
            v0 = *(const us8v*)(BgV + kn); v1 = *(const us8v*)(BgV + kn + 8);
        }
#pragma unroll
        for (int kk = 0; kk < 2; kk++) {
            bf16x8 af[4], bu[2], bv2[2];
#pragma unroll
            for (int mi = 0; mi < 4; mi++)
                af[mi] = ldb(&As[wr * 64 + mi * 16 + l15][kk * 32 + lg * 8]);
#pragma unroll
            for (int ni = 0; ni < 2; ni++) {
                bu[ni]  = ldb(&BsU[wc * 32 + ni * 16 + l15][kk * 32 + lg * 8]);
                bv2[ni] = ldb(&BsV[wc * 32 + ni * 16 + l15][kk * 32 + lg * 8]);
            }
#pragma unroll
            for (int mi = 0; mi < 4; mi++)
#pragma unroll
                for (int ni = 0; ni < 2; ni++) {
                    accU[mi][ni] = MFMA16(af[mi], bu[ni], accU[mi][ni]);
                    accV[mi][ni] = MFMA16(af[mi], bv2[ni], accV[mi][ni]);
                }
        }
    }

    const int rbase = bm * 128 + wr * 64 + (lg << 2);
    const int cbase = bn * 64 + wc * 32 + l15;
#pragma unroll
    for (int mi = 0; mi < 4; mi++) {
#pragma unroll
        for (int ni = 0; ni < 2; ni++) {
            int col = cbase + ni * 16;
            float bu_ = bg[col], bv_ = bg[4096 + col];
#pragma unroll
            for (int r = 0; r < 4; r++) {
                int row = rbase + mi * 16 + r;
                float u = accU[mi][ni][r] + bu_;
                float v = accV[mi][ni][r] + bv_;
                float s = v / (1.f + __expf(-v));
                mlp[(size_t)row * 4096 + col] = f2bf(u * s);
            }
        }
    }
}

// ------- RoPE(K) + hi/lo bf16 split, token-order output -------
__global__ __launch_bounds__(256) void rope_split_k(const float* __restrict__ Yk,
                                                    const float* __restrict__ fc,
                                                    unsigned short* __restrict__ KhG,
                                                    unsigned short* __restrict__ KlG) {
    int t = blockIdx.x;           // b*1024 + s
    int s = t & 1023;
    int p = s >> 2;
    int c0 = threadIdx.x * 4;
    const float* y = Yk + (size_t)t * 1024 + c0;
    float v0 = y[0], v1 = y[1], v2 = y[2], v3 = y[3];
    if (p > 0) {
        int d4 = (c0 & 31) >> 1;
        f32x4 f = *(const f32x4*)(fc + ((size_t)(p - 1) * 16 + d4) * 2);
        float w0 = v0 * f[0] - v1 * f[1];
        float w1 = v0 * f[1] + v1 * f[0];
        float w2 = v2 * f[2] - v3 * f[3];
        float w3 = v2 * f[3] + v3 * f[2];
        v0 = w0; v1 = w1; v2 = w2; v3 = w3;
    }
    us4 hi, lo;
    hi[0] = f2bf(v0); lo[0] = f2bf(v0 - bf2f(hi[0]));
    hi[1] = f2bf(v1); lo[1] = f2bf(v1 - bf2f(hi[1]));
    hi[2] = f2bf(v2); lo[2] = f2bf(v2 - bf2f(hi[2]));
    hi[3] = f2bf(v3); lo[3] = f2bf(v3 - bf2f(hi[3]));
    *(us4*)(KhG + (size_t)t * 1024 + c0) = hi;
    *(us4*)(KlG + (size_t)t * 1024 + c0) = lo;
}

// ------- V transpose + hi/lo split: Vt[(b,h)][d (64)][j (1024)] -------
__global__ __launch_bounds__(256) void v_split_t(const float* __restrict__ Yv,
                                                 unsigned short* __restrict__ VtH,
                                                 unsigned short* __restrict__ VtL) {
    const int jc = blockIdx.x, h = blockIdx.y, b = blockIdx.z;   // (16,16,2)
    __shared__ float tile[64][65];
    const int t = threadIdx.x;
    {
        const int jr = t >> 2, dc = (t & 3) * 16;
        const float* src = Yv + ((size_t)(b * 1024 + jc * 64 + jr) << 10) + h * 64 + dc;
        *(f32x4*)&tile[jr][dc]      = *(const f32x4*)src;
        *(f32x4*)&tile[jr][dc + 4]  = *(const f32x4*)(src + 4);
        *(f32x4*)&tile[jr][dc + 8]  = *(const f32x4*)(src + 8);
        *(f32x4*)&tile[jr][dc + 12] = *(const f32x4*)(src + 12);
    }
    __syncthreads();
    const int d = t >> 2, js = (t & 3) * 16;
    us8v h0, h1, l0, l1;
#pragma unroll
    for (int n = 0; n < 16; n++) {
        float val = tile[js + n][d];
        unsigned short hh = f2bf(val);
        unsigned short ll = f2bf(val - bf2f(hh));
        if (n < 8) { h0[n] = hh; l0[n] = ll; }
        else       { h1[n - 8] = hh; l1[n - 8] = ll; }
    }
    size_t ob = (((size_t)(b * 16 + h) * 64 + d) << 10) + jc * 64 + js;
    *(us8v*)(VtH + ob) = h0; *(us8v*)(VtH + ob + 8) = h1;
    *(us8v*)(VtL + ob) = l0; *(us8v*)(VtL + ob + 8) = l1;
}

// =====================================================================
// pass_0: Z1/Z2 denominators. K-HI ONLY (2 MFMAs/half; dropped K-lo term
// perturbs Z by ~0.1% row-uniform -> RMS-invariant downstream). kc range
// SPLIT across 2 blocks (even/odd chunks) -> grid 1024 (4 blocks/CU);
// partial Z accumulated into MZ via fp32 atomicAdd (MZ zeroed by prep).
// LDS = Kh only (9.2 KB). RoPE(Q) fused.
// =====================================================================
__global__ __launch_bounds__(256) void pass_0(const float* __restrict__ Yq,
                                              const float* __restrict__ fc,
                                              const unsigned short* __restrict__ KhG,
                                              float* __restrict__ MZ) {
    const int blk = blockIdx.x;           // 1024 blocks, heavy qc first
    const int qc   = 15 - (blk >> 6);
    const int half = blk & 1;
    const int h    = (blk >> 1) & 15;
    const int b    = (blk >> 5) & 1;
    const int t = threadIdx.x;
    const int lane = t & 63, w = t >> 6;
    const int l15 = lane & 15, lg = lane >> 4;

    __shared__ __align__(16) unsigned short Kh[64][72];

    us8v qh[2], ql[2];
    {
        const int srq = qc * 64 + w * 16 + l15;
        const int p = srq >> 2;
        const float* qp = Yq + ((size_t)(b * 1024 + srq) << 10) + h * 64 + lg * 8;
#pragma unroll
        for (int H = 0; H < 2; H++) {
            int dd = lg * 8 + H * 32;
            f32x4 a = rope4(*(const f32x4*)(qp + H * 32), fc, p, dd);
            f32x4 c = rope4(*(const f32x4*)(qp + H * 32 + 4), fc, p, dd + 4);
            split8(a, c, qh[H], ql[H]);
        }
    }
    const int dq0 = w * 16 + (lg << 2);

    const int srow = t >> 2, ssub = t & 3;
    const int ptk = 4 * (srow & 15) + (srow >> 4);
    const unsigned short* KhB = KhG + ((size_t)(b * 1024) << 10) + h * 64;

    float z1r[4] = {0.f, 0.f, 0.f, 0.f};
    float z2r[4] = {0.f, 0.f, 0.f, 0.f};

    us8v rkh0, rkh1;
    {
        const int kc0 = (half <= qc) ? half : 0;
        const unsigned short* kh = KhB + ((size_t)(kc0 * 64 + ptk) << 10) + ssub * 16;
        rkh0 = *(const us8v*)kh; rkh1 = *(const us8v*)(kh + 8);
    }
    for (int kc = half; kc <= qc; kc += 2) {
        __syncthreads();
        *(us8v*)&Kh[srow][ssub * 16]     = rkh0;
        *(us8v*)&Kh[srow][ssub * 16 + 8] = rkh1;
        __syncthreads();
        if (kc + 2 <= qc) {
            const unsigned short* kh = KhB + ((size_t)((kc + 2) * 64 + ptk) << 10) + ssub * 16;
            rkh0 = *(const us8v*)kh; rkh1 = *(const us8v*)(kh + 8);
        }
        const int kpos = kc * 16 + l15;
#pragma unroll
        for (int kf = 0; kf < 4; kf++) {
            const int krow = kf * 16 + l15;
            const int kcol = lg * 8;
            bf16x8 b1h = ldb(&Kh[krow][kcol]);
            bf16x8 b2h = ldb(&Kh[krow][32 + kcol]);
            f32x4 s1 = {}, s2 = {};
            s1 = MFMA16(__builtin_bit_cast(bf16x8, ql[0]), b1h, s1);
            s1 = MFMA16(__builtin_bit_cast(bf16x8, qh[0]), b1h, s1);
            s2 = MFMA16(__builtin_bit_cast(bf16x8, ql[1]), b2h, s2);
            s2 = MFMA16(__builtin_bit_cast(bf16x8, qh[1]), b2h, s2);
#pragma unroll
            for (int r = 0; r < 4; r++) {
                int pq = (qc * 64 + dq0 + r) >> 2;
                if (kpos <= pq) {
                    z1r[r] += __expf(fabsf(s1[r] * SCALING));
                    z2r[r] += __expf(fabsf(s2[r] * SCALING));
                }
            }
        }
    }
#pragma unroll
    for (int r = 0; r < 4; r++) {
        float a = z1r[r];
        a += __shfl_xor(a, 1); a += __shfl_xor(a, 2);
        a += __shfl_xor(a, 4); a += __shfl_xor(a, 8);
        float c = z2r[r];
        c += __shfl_xor(c, 1); c += __shfl_xor(c, 2);
        c += __shfl_xor(c, 4); c += __shfl_xor(c, 8);
        if (l15 == 0) {
            int s2i = qc * 64 + dq0 + r;
            float* mp = MZ + (((size_t)(b * 16 + h) << 10) + s2i) * 2;
            atomicAdd(mp, a);
            atomicAdd(mp + 1, c);
        }
    }
}

// =====================================================================
// pass_1: weights + G colsums + AV (Z from MZ). Pipelined K+V staging,
// wave-private W tiles, per-wave Gacc slices, RoPE(Q) fused.
// =====================================================================
__global__ __launch_bounds__(256) void pass_1(const float* __restrict__ Yq,
                                              const float* __restrict__ fc,
                                              const unsigned short* __restrict__ KhG,
                                              const unsigned short* __restrict__ KlG,
                                              const unsigned short* __restrict__ VtH,
                                              const unsigned short* __restrict__ VtL,
                                              const float* __restrict__ MZ,
                                              const float* __restrict__ lamp,
                                              float* __restrict__ G,
                                              float* __restrict__ AOp) {
    const int blk = blockIdx.x;
    const int qc = 15 - (blk >> 5);
    const int h  = blk & 15;
    const int b  = (blk >> 4) & 1;
    const int t = threadIdx.x;
    const int lane = t & 63, w = t >> 6;
    const int l15 = lane & 15, lg = lane >> 4;

    __shared__ __align__(16) unsigned short Kh[64][72];
    __shared__ __align__(16) unsigned short Kl[64][72];
    __shared__ __align__(16) unsigned short Vth[64][72];
    __shared__ __align__(16) unsigned short Vtl[64][72];
    __shared__ __align__(16) unsigned short Wh[64][72];
    __shared__ __align__(16) unsigned short Wl[64][72];
    __shared__ float Gacc[4][1024];

    for (int i = t; i < 4096; i += 256) ((float*)Gacc)[i] = 0.f;

    us8v qh[2], ql[2];
    {
        const int srq = qc * 64 + w * 16 + l15;
        const int p = srq >> 2;
        const float* qp = Yq + ((size_t)(b * 1024 + srq) << 10) + h * 64 + lg * 8;
#pragma unroll
        for (int H = 0; H < 2; H++) {
            int dd = lg * 8 + H * 32;
            f32x4 a = rope4(*(const f32x4*)(qp + H * 32), fc, p, dd);
            f32x4 c = rope4(*(const f32x4*)(qp + H * 32 + 4), fc, p, dd + 4);
            split8(a, c, qh[H], ql[H]);
        }
    }
    const int dq0 = w * 16 + (lg << 2);

    float z1r[4], z2r[4];
#pragma unroll
    for (int r = 0; r < 4; r++) {
        int s2i = qc * 64 + dq0 + r;
        f32x2 zz = *(const f32x2*)(MZ + (((size_t)(b * 16 + h) << 10) + s2i) * 2);
        z1r[r] = 1.f / fmaxf(zz[0], 1e-20f);
        z2r[r] = 1.f / fmaxf(zz[1], 1e-20f);
    }

    const int srow = t >> 2, ssub = t & 3;
    const int ptk = 4 * (srow & 15) + (srow >> 4);
    const unsigned short* KhB = KhG + ((size_t)(b * 1024) << 10) + h * 64;
    const unsigned short* KlB = KlG + ((size_t)(b * 1024) << 10) + h * 64;
    const unsigned short* VhB = VtH + (((size_t)(b * 16 + h) * 64 + srow) << 10) + ssub * 256;
    const unsigned short* VlB = VtL + (((size_t)(b * 16 + h) * 64 + srow) << 10) + ssub * 256;
    const float lam = *lamp;

    f32x4 ao[4] = {};

    us8v rkh0, rkh1, rkl0, rkl1, rvh0, rvh1, rvl0, rvl1;
    {
        const unsigned short* kh = KhB + ((size_t)ptk << 10) + ssub * 16;
        const unsigned short* kl = KlB + ((size_t)ptk << 10) + ssub * 16;
        rkh0 = *(const us8v*)kh; rkh1 = *(const us8v*)(kh + 8);
        rkl0 = *(const us8v*)kl; rkl1 = *(const us8v*)(kl + 8);
        rvh0 = *(const us8v*)VhB; rvh1 = *(const us8v*)(VhB + 8);
        rvl0 = *(const us8v*)VlB; rvl1 = *(const us8v*)(VlB + 8);
    }
    for (int kc = 0; kc <= qc; kc++) {
        __syncthreads();
        *(us8v*)&Kh[srow][ssub * 16]      = rkh0;
        *(us8v*)&Kh[srow][ssub * 16 + 8]  = rkh1;
        *(us8v*)&Kl[srow][ssub * 16]      = rkl0;
        *(us8v*)&Kl[srow][ssub * 16 + 8]  = rkl1;
        *(us8v*)&Vth[srow][ssub * 16]     = rvh0;
        *(us8v*)&Vth[srow][ssub * 16 + 8] = rvh1;
        *(us8v*)&Vtl[srow][ssub * 16]     = rvl0;
        *(us8v*)&Vtl[srow][ssub * 16 + 8] = rvl1;
        __syncthreads();
        if (kc < qc) {
            const unsigned short* kh = KhB + ((size_t)((kc + 1) * 64 + ptk) << 10) + ssub * 16;
            const unsigned short* kl = KlB + ((size_t)((kc + 1) * 64 + ptk) << 10) + ssub * 16;
            rkh0 = *(const us8v*)kh; rkh1 = *(const us8v*)(kh + 8);
            rkl0 = *(const us8v*)kl; rkl1 = *(const us8v*)(kl + 8);
            const unsigned short* vh = VhB + (kc + 1) * 16;
            const unsigned short* vl = VlB + (kc + 1) * 16;
            rvh0 = *(const us8v*)vh; rvh1 = *(const us8v*)(vh + 8);
            rvl0 = *(const us8v*)vl; rvl1 = *(const us8v*)(vl + 8);
        }
        const int kpos = kc * 16 + l15;
#pragma unroll
        for (int kf = 0; kf < 4; kf++) {
            const int krow = kf * 16 + l15;
            const int kcol = lg * 8;
            bf16x8 b1h = ldb(&Kh[krow][kcol]),      b1l = ldb(&Kl[krow][kcol]);
            bf16x8 b2h = ldb(&Kh[krow][32 + kcol]), b2l = ldb(&Kl[krow][32 + kcol]);
            f32x4 s1 = {}, s2 = {};
            s1 = MFMA16(__builtin_bit_cast(bf16x8, ql[0]), b1h, s1);
            s1 = MFMA16(__builtin_bit_cast(bf16x8, qh[0]), b1l, s1);
            s1 = MFMA16(__builtin_bit_cast(bf16x8, qh[0]), b1h, s1);
            s2 = MFMA16(__builtin_bit_cast(bf16x8, ql[1]), b2h, s2);
            s2 = MFMA16(__builtin_bit_cast(bf16x8, qh[1]), b2l, s2);
            s2 = MFMA16(__builtin_bit_cast(bf16x8, qh[1]), b2h, s2);
            const int kli = kf * 16 + l15;
            float colsum = 0.f;
#pragma unroll
            for (int r = 0; r < 4; r++) {
                int pq = (qc * 64 + dq0 + r) >> 2;
                float wv = 0.f, a1 = 0.f;
                if (kpos <= pq) {
                    float t1 = s1[r] * SCALING, t2 = s2[r] * SCALING;
                    float sg1 = (t1 > 0.f) ? 1.f : ((t1 < 0.f) ? -1.f : 0.f);
                    float sg2 = (t2 > 0.f) ? 1.f : ((t2 < 0.f) ? -1.f : 0.f);
                    a1 = sg1 * __expf(fabsf(t1)) * z1r[r];
                    wv = a1 - lam * (sg2 * __expf(fabsf(t2)) * z2r[r]);
                }
                colsum += a1;
                unsigned short hh = f2bf(wv);
                Wh[dq0 + r][kli] = hh;
                Wl[dq0 + r][kli] = f2bf(wv - bf2f(hh));
            }
            colsum += __shfl_xor(colsum, 16);
            colsum += __shfl_xor(colsum, 32);
            if (lane < 16) Gacc[w][kf * 256 + kc * 16 + lane] = colsum;
        }
        // No barrier: Wh/Wl rows [w*16, w*16+16) are wave-private.
#pragma unroll
        for (int kh2 = 0; kh2 < 2; kh2++) {
            bf16x8 wah = ldb(&Wh[w * 16 + l15][kh2 * 32 + lg * 8]);
            bf16x8 wal = ldb(&Wl[w * 16 + l15][kh2 * 32 + lg * 8]);
#pragma unroll
            for (int df = 0; df < 4; df++) {
                bf16x8 vbh = ldb(&Vth[df * 16 + l15][kh2 * 32 + lg * 8]);
                bf16x8 vbl = ldb(&Vtl[df * 16 + l15][kh2 * 32 + lg * 8]);
                ao[df] = MFMA16(wah, vbl, ao[df]);
                ao[df] = MFMA16(wal, vbh, ao[df]);
                ao[df] = MFMA16(wah, vbh, ao[df]);
            }
        }
    }

#pragma unroll
    for (int df = 0; df < 4; df++) {
#pragma unroll
        for (int r = 0; r < 4; r++) {
            int tq = qc * 64 + dq0 + r;
            int qrow = ((tq & 3) << 8) + (tq >> 2);
            AOp[((((size_t)(b * 16 + h)) << 10) + qrow) * 64 + df * 16 + l15] = ao[df][r];
        }
    }

    __syncthreads();
    float* Gb = G + ((size_t)(b * 16 + h) << 10);
    const int limp = (qc + 1) << 4;
    for (int idx = t; idx < 1024; idx += 256) {
        if ((idx & 255) < limp) {
            float s = Gacc[0][idx] + Gacc[1][idx] + Gacc[2][idx] + Gacc[3][idx];
            atomicAdd(&Gb[idx], s);
        }
    }
}

// -------- pass_2a: per (b,h) masked prefix GV[p][d] = sum_{pos<=p} G.v --------
__global__ __launch_bounds__(256) void pass_2a(const float* __restrict__ G,
                                               const float* __restrict__ Yv,
                                               float* __restrict__ GVpre) {
    const int h = blockIdx.x, b = blockIdx.y;
    const int t = threadIdx.x;
    __shared__ float Gl[1024];
    __shared__ float S[256][64];
    __shared__ float segsum[4][64];
    for (int i = t; i < 1024; i += 256) Gl[i] = G[((size_t)(b * 16 + h) << 10) + i];
    __syncthreads();
    const int d = t & 63, pg = t >> 6;
    const float* Yvb = Yv + ((size_t)b << 20) + h * 64 + d;
    for (int p0 = 0; p0 < 64; p0++) {
        int pos = pg * 64 + p0;
        float s = 0.f;
#pragma unroll
        for (int sq = 0; sq < 4; sq++) {
            int j = (sq << 8) + pos;
            s += Gl[j] * Yvb[(size_t)j << 10];
        }
        S[pos][d] = s;
    }
    __syncthreads();
    float acc = 0.f;
    for (int p0 = 0; p0 < 64; p0++) {
        int pos = pg * 64 + p0;
        acc += S[pos][d];
        S[pos][d] = acc;
    }
    segsum[pg][d] = acc;
    __syncthreads();
    float off = 0.f;
    for (int g = 0; g < pg; g++) off += segsum[g][d];
    float* gv = GVpre + (((size_t)(b * 16 + h)) << 14) + d;
    for (int p0 = 0; p0 < 64; p0++) {
        int pos = pg * 64 + p0;
        gv[pos << 6] = S[pos][d] + off;
    }
}

// -------- pass_2b: ao = AOp + (lam/1024)*GV[pq]; RMS; bf16 store --------
__global__ __launch_bounds__(256) void pass_2b(const float* __restrict__ AOp,
                                               const float* __restrict__ GVpre,
                                               const float* __restrict__ lamp,
                                               const float* __restrict__ wan,
                                               unsigned short* __restrict__ aoS) {
    const int qg = blockIdx.x;
    const int h = blockIdx.y, b = blockIdx.z;
    const int t = threadIdx.x;
    const int d = t & 63, rg = t >> 6;
    const float lamg = (*lamp) * (1.f / 1024.f);
    const float wv = wan[d];
    const float* aob = AOp + ((((size_t)(b * 16 + h)) << 10) + (qg << 8)) * 64 + d;
    const float* gvb = GVpre + (((size_t)(b * 16 + h)) << 14) + d;
    unsigned short* ob = aoS + ((size_t)b << 20) + ((size_t)h << 16) + ((size_t)(qg << 8) << 6) + d;
    for (int p0 = 0; p0 < 64; p0++) {
        int pq = p0 * 4 + rg;
        float ao = aob[(size_t)pq << 6] + lamg * gvb[(size_t)pq << 6];
        float ss = ao * ao;
#pragma unroll
        for (int o = 1; o < 64; o <<= 1) ss += __shfl_xor(ss, o);
        float rr_ = rsqrtf(ss * (1.f / 64.f) + EPS_ATTN);
        ob[(size_t)pq << 6] = f2bf(ao * rr_ * wv);
    }
}

extern "C" void kernel_launch(void* const* d_in, const int* in_sizes, int n_in,
                              void* d_out, int out_size, void* d_ws, size_t ws_size,
                              hipStream_t stream) {
    const float* x    = (const float*)d_in[0];
    const float* fc   = (const float*)d_in[1];
    const float* w1   = (const float*)d_in[2];
    const float* w2   = (const float*)d_in[3];
    const float* Wq   = (const float*)d_in[4];
    const float* bq   = (const float*)d_in[5];
    const float* Wk   = (const float*)d_in[6];
    const float* bk   = (const float*)d_in[7];
    const float* Wv   = (const float*)d_in[8];
    const float* bv   = (const float*)d_in[9];
    const float* Wo   = (const float*)d_in[10];
    const float* bo   = (const float*)d_in[11];
    const float* lq1  = (const float*)d_in[12];
    const float* lk1  = (const float*)d_in[13];
    const float* lq2  = (const float*)d_in[14];
    const float* lk2  = (const float*)d_in[15];
    const float* wan  = (const float*)d_in[16];
    const float* Wg   = (const float*)d_in[17];
    const float* bg   = (const float*)d_in[18];
    const float* Wout = (const float*)d_in[19];
    const float* bout = (const float*)d_in[20];

    char* ws = (char*)d_ws;
    const size_t MB = 1024 * 1024;
    // Layout (peak 49 MB):
    float* G    = (float*)(ws);                     // [0, 128K)
    float* lam  = (float*)(ws + 256 * 1024);        // 4 B
    float* MZ   = (float*)(ws + 384 * 1024);        // [384K, 640K) raw Z1/Z2 per row (zeroed by prep)
    unsigned short* hH = (unsigned short*)(ws + 1 * MB);   // [1,5)  (dead after QKV)
    unsigned short* hL = (unsigned short*)(ws + 5 * MB);   // [5,9)
    float* Yq   = (float*)(ws + 9 * MB);            // [9,17)  (un-roped; rope fused)
    float* Yk   = (float*)(ws + 17 * MB);           // [17,25) (dead after rope_split_k)
    float* Yv   = (float*)(ws + 25 * MB);           // [25,33) (dead after pass_2a)
    unsigned short* WqH = (unsigned short*)(ws + 33 * MB); // [33,35) (dead after QKV)
    unsigned short* WqL = (unsigned short*)(ws + 35 * MB); // [35,37)
    unsigned short* WkH = (unsigned short*)(ws + 37 * MB); // [37,39)
    unsigned short* WkL = (unsigned short*)(ws + 39 * MB); // [39,41)
    unsigned short* WvH = (unsigned short*)(ws + 41 * MB); // [41,43)
    unsigned short* WvL = (unsigned short*)(ws + 43 * MB); // [43,45)
    unsigned short* WoB = (unsigned short*)(ws + 45 * MB); // [45,47) (converted pre-QKV; dead after Wo gemm)
    float* AOp  = (float*)(ws + 33 * MB);           // reuse [33,41) after QKV
    float* GVpre= (float*)(ws + 41 * MB);           // reuse [41,43) after QKV
    unsigned short* KhG = (unsigned short*)(ws + 1 * MB);  // reuse [1,5)  (hH dead)
    unsigned short* KlG = (unsigned short*)(ws + 5 * MB);  // reuse [5,9)  (hL dead)
    unsigned short* VtH = (unsigned short*)(ws + 17 * MB); // reuse [17,21) (Yk dead)
    unsigned short* VtL = (unsigned short*)(ws + 21 * MB); // reuse [21,25)
    unsigned short* aoS = (unsigned short*)(ws + 1 * MB);  // reuse [1,5)  (KhG dead after pass_1)
    float* X1           = (float*)(ws + 9 * MB);           // reuse [9,17) (Yq dead after pass_1)
    unsigned short* h2b = (unsigned short*)(ws + 5 * MB);  // reuse [5,9)  (KlG dead)
    unsigned short* mlp = (unsigned short*)(ws + 17 * MB); // reuse [17,33) (VtH/L, Yv dead)
    unsigned short* WuB = (unsigned short*)(ws + 33 * MB); // reuse [33,41) after pass_2b (AOp dead)
    unsigned short* WvB2= (unsigned short*)(ws + 41 * MB); // reuse [41,49) after Wo gemm (GVpre/WoB dead)
    unsigned short* WoutB=(unsigned short*)(ws + 33 * MB); // reuse [33,41) after gate (WuB dead)

    prep<<<96, 256, 0, stream>>>(G, MZ, lam, lq1, lk1, lq2, lk2);
    rms_split<<<2048, 256, 0, stream>>>(x, w1, hH, hL, EPS_DEF);
    // QKV weight splits + Wo plain convert, one fused launch.
    cvt_wsplit<<<dim3(1024, 4), 256, 0, stream>>>(Wq, Wk, Wv, Wo,
                                                  WqH, WqL, WkH, WkL, WvH, WvL, WoB, 262144);
    gemm_qkv_ps<<<dim3(32, 16, 3), 256, 0, stream>>>(hH, hL, WqH, WqL, WkH, WkL, WvH, WvL,
                                                     bq, bk, bv, Yq, Yk, Yv);
    rope_split_k<<<2048, 256, 0, stream>>>(Yk, fc, KhG, KlG);
    v_split_t<<<dim3(16, 16, 2), 256, 0, stream>>>(Yv, VtH, VtL);
    pass_0<<<1024, 256, 0, stream>>>(Yq, fc, KhG, MZ);
    pass_1<<<512, 256, 0, stream>>>(Yq, fc, KhG, KlG, VtH, VtL, MZ, lam, G, AOp);
    pass_2a<<<dim3(16, 2), 256, 0, stream>>>(G, Yv, GVpre);
    pass_2b<<<dim3(4, 16, 2), 256, 0, stream>>>(AOp, GVpre, lam, wan, aoS);
    dim3 gmf(32, 16);
    gemm_mfma_wb<<<gmf, 256, 0, stream>>>(aoS, WoB, bo, x, X1, 2048, 1024, 1024);
    // Gate weights (both halves), one fused launch (AOp/GVpre/WoB dead).
    cvt_gate2<<<dim3(4096, 2), 256, 0, stream>>>(Wg, WuB, WvB2, 1048576);
    rms_kernel<1><<<2048, 256, 0, stream>>>(X1, w2, h2b, EPS_DEF);
    gemm_gate_wb<<<dim3(16, 64), 256, 0, stream>>>(h2b, WuB, WvB2, bg, mlp);
    // Pre-convert Wout into [33,41) (WuB dead after gate).
    cvt_bf16<<<4096, 256, 0, stream>>>(Wout, WoutB, 1048576);
    // FINAL OUTPUT IS FP32.
    gemm_mfma_wb<<<gmf, 256, 0, stream>>>(mlp, WoutB, bout, X1, (float*)d_out, 2048, 1024, 4096);
}